// Round 1
// baseline (2900.045 us; speedup 1.0000x reference)
//
#include <hip/hip_runtime.h>

typedef _Float16 half8 __attribute__((ext_vector_type(8)));
typedef float float4v __attribute__((ext_vector_type(4)));
typedef float float2v __attribute__((ext_vector_type(2)));
typedef unsigned short u16;
typedef unsigned int u32;
typedef unsigned long long u64;

// ---------- workspace layout (bytes); total ~300 KB ----------
// hx is now two f16 planes in [slot][d][g][row16][unit256] order:
//   hi plane: 2*2*4*16*256 u16 = 128 KB, lo plane: +128 KB  => 256 KB total
#define OFF_HX    ((size_t)0)
#define OFF_FLAGS ((size_t)262144)   /* flags[sg*8+q8], contiguous per group */
#define OFF_MASK  ((size_t)266240)

#define LO_SCALE   2048.0f
#define LO_ISCALE  (1.0f / 2048.0f)

__device__ __forceinline__ u16 h2u(_Float16 h) {
  union { _Float16 h; u16 u; } u; u.h = h; return u.u;
}
__device__ __forceinline__ int imin2(int a, int b) { return a < b ? a : b; }
__device__ __forceinline__ float ftanh(float x) {
  float e = __expf(x + x);
  return 1.0f - 2.0f * __builtin_amdgcn_rcpf(e + 1.0f);
}
__device__ __forceinline__ float clamp30(float v) {
  return fminf(30.0f, fmaxf(-30.0f, v));
}
__device__ __forceinline__ void split2(float v, _Float16& hi, _Float16& lo) {
  hi = (_Float16)v;
  lo = (_Float16)((v - (float)hi) * LO_SCALE);
}

// ---------------- mask[t][b] = any(x[b,t,:] != 0); also zero flags ----------------
__global__ __launch_bounds__(256) void k_mask(const float* __restrict__ x,
                                              unsigned char* __restrict__ mask,
                                              int* __restrict__ flags) {
  if (blockIdx.x < 4) flags[blockIdx.x * 256 + threadIdx.x] = 0;
  int w = threadIdx.x >> 6, l = threadIdx.x & 63;
  int row = blockIdx.x * 4 + w;  // row = b*512 + t, 0..32767
  const float4v* p = (const float4v*)(x + (size_t)row * 256 + l * 4);
  float4v v = *p;
  int nz = (v[0] != 0.f) || (v[1] != 0.f) || (v[2] != 0.f) || (v[3] != 0.f);
  unsigned long long bal = __ballot(nz);
  if (l == 0) {
    int b = row >> 9, t = row & 511;
    mask[t * 64 + b] = (bal != 0ull) ? 1 : 0;
  }
}

// ---------------- fused sequential scan, split-f16, direct-LLC h exchange ----------------
// 64 WGs: bid = q8*8 + (d*4+g). Handoff: writer stores h as split hi/lo f16
// PLANES in [row][unit] order (A-fragment friendly) with relaxed agent atomics;
// B4 drains vmcnt(0); flag store. Readers spin on the group's 8-flag vector,
// then load their MFMA A-fragments DIRECTLY from the planes (8B relaxed agent
// atomic loads) -- no LDS h staging, no B2 barrier, no reader-side split.
// Phase A (x@Wk) + next-x staging execute under the h-load latency shadow.
// `out` stores are issued after the flag so they never sit in the B4 drain.
__global__ __launch_bounds__(256, 1) void k_scan(const float* __restrict__ Wk_f,
                                                 const float* __restrict__ Wr_f,
                                                 const float* __restrict__ b_f,
                                                 const float* __restrict__ Wk_b,
                                                 const float* __restrict__ Wr_b,
                                                 const float* __restrict__ b_b,
                                                 const float* __restrict__ x,
                                                 const unsigned char* __restrict__ mask,
                                                 float* __restrict__ hx,
                                                 int* __restrict__ flags,
                                                 float* __restrict__ out) {
  __shared__ u16 xhi[2][16][264], xlo[2][16][264]; // f16 x tile, double-buffered
  __shared__ float zb[4][16][34];                  // [gate][row][unitcol+pad]

  int bid = blockIdx.x;
  int sg = bid & 7, q8 = bid >> 3;
  int d = sg >> 2, g = sg & 3;
  int tid = threadIdx.x;
  int w = tid >> 6, l = tid & 63;
  int p = w >> 1, sl = w & 1;
  int lg = l >> 4, li = l & 15;
  int r = tid >> 4, u2 = tid & 15;  // phase-D/staging ownership: row r, units 2u2,2u2+1
  const float* Wk = d ? Wk_b : Wk_f;
  const float* Wr = d ? Wr_b : Wr_f;
  const float* bias = d ? b_b : b_f;

  int ncol0 = 256 * (2 * p) + 32 * q8 + 16 * sl + li;  // gate 2p column
  int ncol1 = ncol0 + 256;                             // gate 2p+1

  // Register-resident split weight B-fragments (m92-verified addressing).
  half8 wkh[2][8], wkl[2][8], wrh[2][8], wrl[2][8];
#pragma unroll
  for (int kk = 0; kk < 8; ++kk) {
#pragma unroll
    for (int jj = 0; jj < 8; ++jj) {
      int k = 32 * kk + 8 * lg + jj;
      _Float16 hi, lo;
      split2(Wk[(size_t)k * 1024 + ncol0], hi, lo); wkh[0][kk][jj] = hi; wkl[0][kk][jj] = lo;
      split2(Wk[(size_t)k * 1024 + ncol1], hi, lo); wkh[1][kk][jj] = hi; wkl[1][kk][jj] = lo;
      split2(Wr[(size_t)k * 1024 + ncol0], hi, lo); wrh[0][kk][jj] = hi; wrl[0][kk][jj] = lo;
      split2(Wr[(size_t)k * 1024 + ncol1], hi, lo); wrh[1][kk][jj] = hi; wrl[1][kk][jj] = lo;
    }
  }
  float bs0 = bias[ncol0], bs1 = bias[ncol1];

  float cs0 = 0.f, cs1 = 0.f, hs0 = 0.f, hs1 = 0.f;
  int fl_self = sg * 8 + q8;

  // x staging: thread covers row r, 16 cols at c0 of the 16x256 fp32 tile
  int c0 = 16 * u2;
  const float* xrow = x + ((size_t)(16 * g + r) * 512) * 256 + c0;
  {
    int t0 = d ? 511 : 0;
    const float4v* xp = (const float4v*)(xrow + (size_t)t0 * 256);
    float va[16];
    *(float4v*)&va[0] = xp[0]; *(float4v*)&va[4] = xp[1];
    *(float4v*)&va[8] = xp[2]; *(float4v*)&va[12] = xp[3];
    half8 h0v, h1v, l0v, l1v;
#pragma unroll
    for (int j = 0; j < 8; ++j) {
      _Float16 hi, lo;
      split2(va[j], hi, lo);     h0v[j] = hi; l0v[j] = lo;
      split2(va[8 + j], hi, lo); h1v[j] = hi; l1v[j] = lo;
    }
    *(half8*)(void*)&xhi[0][r][c0] = h0v; *(half8*)(void*)&xhi[0][r][c0 + 8] = h1v;
    *(half8*)(void*)&xlo[0][r][c0] = l0v; *(half8*)(void*)&xlo[0][r][c0 + 8] = l1v;
  }
  __syncthreads();

  for (int ti = 0; ti < 512; ++ti) {
    int t = d ? (511 - ti) : ti;
    int buf = ti & 1;

    // issue next step's x loads + this step's mask load early
    float4v xa0, xa1, xa2, xa3;
    if (ti < 511) {
      int tn = d ? (510 - ti) : (ti + 1);
      const float4v* xp = (const float4v*)(xrow + (size_t)tn * 256);
      xa0 = xp[0]; xa1 = xp[1]; xa2 = xp[2]; xa3 = xp[3];
    }
    int mk = mask[t * 64 + 16 * g + r];

    // phase B: spin on the group's 8-flag vector, then issue all h-fragment
    // loads (relaxed agent atomics, control-dependent on the flag observation).
    double dhv[16], dlv[16];
    if (ti > 0) {
      const u64* fp8 = (const u64*)(const void*)(flags + sg * 8);
      for (;;) {
        u64 f0 = __hip_atomic_load(fp8 + 0, __ATOMIC_RELAXED, __HIP_MEMORY_SCOPE_AGENT);
        u64 f1 = __hip_atomic_load(fp8 + 1, __ATOMIC_RELAXED, __HIP_MEMORY_SCOPE_AGENT);
        u64 f2 = __hip_atomic_load(fp8 + 2, __ATOMIC_RELAXED, __HIP_MEMORY_SCOPE_AGENT);
        u64 f3 = __hip_atomic_load(fp8 + 3, __ATOMIC_RELAXED, __HIP_MEMORY_SCOPE_AGENT);
        int mn = imin2(imin2(imin2((int)(u32)f0, (int)(u32)(f0 >> 32)),
                             imin2((int)(u32)f1, (int)(u32)(f1 >> 32))),
                       imin2(imin2((int)(u32)f2, (int)(u32)(f2 >> 32)),
                             imin2((int)(u32)f3, (int)(u32)(f3 >> 32))));
        if (mn >= ti) break;
        __builtin_amdgcn_s_sleep(1);
      }
      int slot2 = (ti - 1) & 1;
      // A-fragment row = li; units 32kk+8lg..+7 => doubles 8kk+2lg, +1 within row
      const double* hb = (const double*)(const void*)hx +
          ((((size_t)(slot2 * 2 + d) * 4 + g) * 16 + li) * 64 + 2 * lg);
      const double* lb = hb + 16384;  // lo plane: +65536 u16 = +16384 doubles
#pragma unroll
      for (int kk = 0; kk < 8; ++kk) {
        dhv[2 * kk]     = __hip_atomic_load(hb + 8 * kk,     __ATOMIC_RELAXED, __HIP_MEMORY_SCOPE_AGENT);
        dhv[2 * kk + 1] = __hip_atomic_load(hb + 8 * kk + 1, __ATOMIC_RELAXED, __HIP_MEMORY_SCOPE_AGENT);
        dlv[2 * kk]     = __hip_atomic_load(lb + 8 * kk,     __ATOMIC_RELAXED, __HIP_MEMORY_SCOPE_AGENT);
        dlv[2 * kk + 1] = __hip_atomic_load(lb + 8 * kk + 1, __ATOMIC_RELAXED, __HIP_MEMORY_SCOPE_AGENT);
      }
    }

    // phase A: z = b + x@Wk (split) -- pure LDS/reg work, hides h-load latency
    float4v zm0 = {bs0, bs0, bs0, bs0}, zm1 = {bs1, bs1, bs1, bs1};
    float4v zc0 = {0.f, 0.f, 0.f, 0.f}, zc1 = {0.f, 0.f, 0.f, 0.f};
#pragma unroll
    for (int kk = 0; kk < 8; ++kk) {
      half8 axh = *(const half8*)(const void*)&xhi[buf][li][32 * kk + 8 * lg];
      half8 axl = *(const half8*)(const void*)&xlo[buf][li][32 * kk + 8 * lg];
      zm0 = __builtin_amdgcn_mfma_f32_16x16x32_f16(axh, wkh[0][kk], zm0, 0, 0, 0);
      zc0 = __builtin_amdgcn_mfma_f32_16x16x32_f16(axh, wkl[0][kk], zc0, 0, 0, 0);
      zc0 = __builtin_amdgcn_mfma_f32_16x16x32_f16(axl, wkh[0][kk], zc0, 0, 0, 0);
      zm1 = __builtin_amdgcn_mfma_f32_16x16x32_f16(axh, wkh[1][kk], zm1, 0, 0, 0);
      zc1 = __builtin_amdgcn_mfma_f32_16x16x32_f16(axh, wkl[1][kk], zc1, 0, 0, 0);
      zc1 = __builtin_amdgcn_mfma_f32_16x16x32_f16(axl, wkh[1][kk], zc1, 0, 0, 0);
    }

    // stage x(t+1) into the other buffer (also under the h-load shadow)
    if (ti < 511) {
      float va[16];
      *(float4v*)&va[0] = xa0; *(float4v*)&va[4] = xa1;
      *(float4v*)&va[8] = xa2; *(float4v*)&va[12] = xa3;
      half8 h0v, h1v, l0v, l1v;
#pragma unroll
      for (int j = 0; j < 8; ++j) {
        _Float16 hi, lo;
        split2(va[j], hi, lo);     h0v[j] = hi; l0v[j] = lo;
        split2(va[8 + j], hi, lo); h1v[j] = hi; l1v[j] = lo;
      }
      *(half8*)(void*)&xhi[buf ^ 1][r][c0] = h0v;
      *(half8*)(void*)&xhi[buf ^ 1][r][c0 + 8] = h1v;
      *(half8*)(void*)&xlo[buf ^ 1][r][c0] = l0v;
      *(half8*)(void*)&xlo[buf ^ 1][r][c0 + 8] = l1v;
    }

    // phase C: z += h @ Wr (split); A-fragments straight from the atomic loads
    if (ti > 0) {
#pragma unroll
      for (int kk = 0; kk < 8; ++kk) {
        union { double dd[2]; half8 hh; } uh, ul;
        uh.dd[0] = dhv[2 * kk]; uh.dd[1] = dhv[2 * kk + 1];
        ul.dd[0] = dlv[2 * kk]; ul.dd[1] = dlv[2 * kk + 1];
        half8 ahh = uh.hh, ahl = ul.hh;
        zm0 = __builtin_amdgcn_mfma_f32_16x16x32_f16(ahh, wrh[0][kk], zm0, 0, 0, 0);
        zc0 = __builtin_amdgcn_mfma_f32_16x16x32_f16(ahh, wrl[0][kk], zc0, 0, 0, 0);
        zc0 = __builtin_amdgcn_mfma_f32_16x16x32_f16(ahl, wrh[0][kk], zc0, 0, 0, 0);
        zm1 = __builtin_amdgcn_mfma_f32_16x16x32_f16(ahh, wrh[1][kk], zm1, 0, 0, 0);
        zc1 = __builtin_amdgcn_mfma_f32_16x16x32_f16(ahh, wrl[1][kk], zc1, 0, 0, 0);
        zc1 = __builtin_amdgcn_mfma_f32_16x16x32_f16(ahl, wrh[1][kk], zc1, 0, 0, 0);
      }
    }
#pragma unroll
    for (int rr = 0; rr < 4; ++rr) {
      zb[2 * p][4 * lg + rr][16 * sl + li] = clamp30(zm0[rr] + zc0[rr] * LO_ISCALE);
      zb[2 * p + 1][4 * lg + rr][16 * sl + li] = clamp30(zm1[rr] + zc1[rr] * LO_ISCALE);
    }
    __syncthreads();  // B3: zb ready

    // phase D: state update -- thread owns row r, units 2u2, 2u2+1
    int uu = 2 * u2;
    float ziA = zb[0][r][uu],     zfA = zb[1][r][uu],     zgA = zb[2][r][uu],     zoA = zb[3][r][uu];
    float ziB = zb[0][r][uu + 1], zfB = zb[1][r][uu + 1], zgB = zb[2][r][uu + 1], zoB = zb[3][r][uu + 1];
    float giA = ftanh(ziA), gfA = ftanh(zfA), ggA = ftanh(zgA), goA = ftanh(zoA);
    float giB = ftanh(ziB), gfB = ftanh(zfB), ggB = ftanh(zgB), goB = ftanh(zoB);
    float cnA = gfA * cs0 + giA * ggA;
    float cnB = gfB * cs1 + giB * ggB;
    float hnA = goA * ftanh(cnA);
    float hnB = goB * ftanh(cnB);
    bool mkb = mk != 0;
    cs0 = mkb ? cnA : cs0; hs0 = mkb ? hnA : hs0;
    cs1 = mkb ? cnB : cs1; hs1 = mkb ? hnB : hs1;
    int slot = ti & 1;
    _Float16 hiA, loA, hiB, loB;
    split2(hs0, hiA, loA); split2(hs1, hiB, loB);
    u32 hp = (u32)h2u(hiA) | ((u32)h2u(hiB) << 16);
    u32 lp = (u32)h2u(loA) | ((u32)h2u(loB) << 16);
    u32* hxw = (u32*)hx;
    size_t rowi = ((size_t)(slot * 2 + d) * 4 + g) * 16 + r;
    __hip_atomic_store(hxw + rowi * 128 + 16 * q8 + u2, hp,
                       __ATOMIC_RELAXED, __HIP_MEMORY_SCOPE_AGENT);
    __hip_atomic_store(hxw + 32768 + rowi * 128 + 16 * q8 + u2, lp,
                       __ATOMIC_RELAXED, __HIP_MEMORY_SCOPE_AGENT);
    __syncthreads();  // B4: drains vmcnt(0) in every wave -> hx globally visible
    if (tid == 0)
      __hip_atomic_store(flags + fl_self, ti + 1, __ATOMIC_RELAXED, __HIP_MEMORY_SCOPE_AGENT);
    // out store post-flag: off the handoff critical path
    float2v ov; ov[0] = hs0; ov[1] = hs1;
    *(float2v*)(out + ((size_t)(16 * g + r) * 512 + t) * 512 + 256 * d + 32 * q8 + uu) = ov;
  }

  // state_h (fp32)
  {
    float2v ov; ov[0] = hs0; ov[1] = hs1;
    *(float2v*)(out + (size_t)16777216 + (size_t)(16 * g + r) * 512 + 256 * d + 32 * q8 + 2 * u2) = ov;
  }
}

extern "C" void kernel_launch(void* const* d_in, const int* in_sizes, int n_in,
                              void* d_out, int out_size, void* d_ws, size_t ws_size,
                              hipStream_t stream) {
  const float* x    = (const float*)d_in[0];
  const float* Wk_f = (const float*)d_in[1];
  const float* Wr_f = (const float*)d_in[2];
  const float* b_f  = (const float*)d_in[3];
  const float* Wk_b = (const float*)d_in[4];
  const float* Wr_b = (const float*)d_in[5];
  const float* b_b  = (const float*)d_in[6];
  char* ws = (char*)d_ws;
  float* hx  = (float*)(ws + OFF_HX);
  int* flags = (int*)(ws + OFF_FLAGS);
  unsigned char* maskp = (unsigned char*)(ws + OFF_MASK);
  float* out = (float*)d_out;

  k_mask<<<8192, 256, 0, stream>>>(x, maskp, flags);
  k_scan<<<64, 256, 0, stream>>>(Wk_f, Wr_f, b_f, Wk_b, Wr_b, b_b, x, maskp, hx, flags, out);
}

// Round 3
// 2077.601 us; speedup vs baseline: 1.3959x; 1.3959x over previous
//
#include <hip/hip_runtime.h>

typedef _Float16 half8 __attribute__((ext_vector_type(8)));
typedef float float4v __attribute__((ext_vector_type(4)));
typedef unsigned short u16;
typedef unsigned short ushort8 __attribute__((ext_vector_type(8)));
typedef unsigned int u32;
typedef unsigned long long u64;

// ---------- workspace layout (bytes); total ~556 KB ----------
// hx: self-validating 8B packets, one per (slot,d,g,q8,row,unit):
//   low 32b = {hi f16, lo f16} of h (pre-split by writer), high 32b = tag (ti+1)
//   2*2*4*8*16*32 packets * 8B = 524288 B
#define OFF_HX    ((size_t)0)
#define OFF_MASK  ((size_t)524288)   /* 32768 B */

#define LO_SCALE   2048.0f
#define LO_ISCALE  (1.0f / 2048.0f)

__device__ __forceinline__ u16 h2u(_Float16 h) {
  union { _Float16 h; u16 u; } u; u.h = h; return u.u;
}
__device__ __forceinline__ float ftanh(float x) {
  // tanh(x) = 1 - 2/(exp(2x)+1); exact saturation for large |x|
  float e = __expf(x + x);
  return 1.0f - 2.0f * __builtin_amdgcn_rcpf(e + 1.0f);
}
__device__ __forceinline__ float clamp30(float v) {
  return fminf(30.0f, fmaxf(-30.0f, v));
}
// split v = hi + lo/2048 (lo pre-scaled so it never hits f16 subnormals)
__device__ __forceinline__ void split2(float v, _Float16& hi, _Float16& lo) {
  hi = (_Float16)v;
  lo = (_Float16)((v - (float)hi) * LO_SCALE);
}

// ---------------- mask[t][b] = any(x[b,t,:] != 0); also zero hx tags ----------------
__global__ __launch_bounds__(256) void k_mask(const float* __restrict__ x,
                                              unsigned char* __restrict__ mask,
                                              u64* __restrict__ hx64) {
  if (blockIdx.x < 256) hx64[(size_t)blockIdx.x * 256 + threadIdx.x] = 0ull;
  int w = threadIdx.x >> 6, l = threadIdx.x & 63;
  int row = blockIdx.x * 4 + w;  // row = b*512 + t, 0..32767
  const float4v* p = (const float4v*)(x + (size_t)row * 256 + l * 4);
  float4v v = *p;
  int nz = (v[0] != 0.f) || (v[1] != 0.f) || (v[2] != 0.f) || (v[3] != 0.f);
  unsigned long long bal = __ballot(nz);
  if (l == 0) {
    int b = row >> 9, t = row & 511;
    mask[t * 64 + b] = (bal != 0ull) ? 1 : 0;
  }
}

// ---------------- fused sequential scan, split-f16 (fp32-grade), fp32 out ----------------
// Handoff redesign vs round-0: SELF-VALIDATING PACKETS.
//   Writer phase D stores, per (row,unit), one 8B relaxed agent atomic:
//     {hi,lo f16 of h} | tag(ti+1)<<32.  8B atomicity => tag can never tear
//   from its payload, so no publish ordering is needed: NO B4 drain, NO flag.
//   Reader phase B polls the packets THEMSELVES until min(tag)>=ti (one LLC
//   round trip, vs round-0's flag-trip + data-trip). First poll round is
//   ISSUED before phase A (speculative, non-blocking) and validated after,
//   hiding its latency under the x@Wk MFMAs. Stale => re-load, tag re-checked.
//   Reader-side split2 is gone: the packet carries the writer's split pair,
//   so numerics are bit-identical to round-0.
// Safety: WG skew is <=1 step (phase B of step ti needs all partners >= ti-1),
//   slot parity (ti&1) double-buffers packets, so a slot polled for tag==ti
//   cannot be overwritten (writer of tag ti+2 first needs OUR h(ti+1), which
//   we publish only after consuming tag-ti data). Removing B4 is safe: zb
//   reuse and hhi cross-step ordering are covered by B2 of the next iteration
//   (D(ti) zb-reads < B2(ti+1) < C(ti+1) zb-writes; D(ti) hhi-writes are to
//   own columns, disjoint from B(ti+1) partner columns, and < B2(ti+1) <
//   C(ti+1) reads).
__global__ __launch_bounds__(256, 1) void k_scan(const float* __restrict__ Wk_f,
                                                 const float* __restrict__ Wr_f,
                                                 const float* __restrict__ b_f,
                                                 const float* __restrict__ Wk_b,
                                                 const float* __restrict__ Wr_b,
                                                 const float* __restrict__ b_b,
                                                 const float* __restrict__ x,
                                                 const unsigned char* __restrict__ mask,
                                                 u64* __restrict__ hx64,
                                                 float* __restrict__ out) {
  __shared__ u16 hhi[16][264], hlo[16][264];       // f16 bits, full 256 units
  __shared__ u16 xhi[2][16][264], xlo[2][16][264]; // f16 x tile, double-buffered
  __shared__ float zb[4][16][34];                  // [gate][row][unitcol+pad]

  int bid = blockIdx.x;
  int sg = bid & 7, q8 = bid >> 3;
  int d = sg >> 2, g = sg & 3;
  int tid = threadIdx.x;
  int w = tid >> 6, l = tid & 63;
  int p = w >> 1, sl = w & 1;
  int lg = l >> 4, li = l & 15;
  const float* Wk = d ? Wk_b : Wk_f;
  const float* Wr = d ? Wr_b : Wr_f;
  const float* bias = d ? b_b : b_f;

  int ncol0 = 256 * (2 * p) + 32 * q8 + 16 * sl + li;  // gate 2p column
  int ncol1 = ncol0 + 256;                             // gate 2p+1

  // Register-resident split weight B-fragments (m92-verified addressing).
  half8 wkh[2][8], wkl[2][8], wrh[2][8], wrl[2][8];
#pragma unroll
  for (int kk = 0; kk < 8; ++kk) {
#pragma unroll
    for (int jj = 0; jj < 8; ++jj) {
      int k = 32 * kk + 8 * lg + jj;
      _Float16 hi, lo;
      split2(Wk[(size_t)k * 1024 + ncol0], hi, lo); wkh[0][kk][jj] = hi; wkl[0][kk][jj] = lo;
      split2(Wk[(size_t)k * 1024 + ncol1], hi, lo); wkh[1][kk][jj] = hi; wkl[1][kk][jj] = lo;
      split2(Wr[(size_t)k * 1024 + ncol0], hi, lo); wrh[0][kk][jj] = hi; wrl[0][kk][jj] = lo;
      split2(Wr[(size_t)k * 1024 + ncol1], hi, lo); wrh[1][kk][jj] = hi; wrl[1][kk][jj] = lo;
    }
  }
  float bs0 = bias[ncol0], bs1 = bias[ncol1];

  for (int i = tid; i < 16 * 264; i += 256) { ((u16*)hhi)[i] = 0; ((u16*)hlo)[i] = 0; }
  float cst[2] = {0.f, 0.f}, hst[2] = {0.f, 0.f};

  // reader-role constants (threads 0..223): partner qq, row m, 16-unit half cc
  int pi = tid >> 5, rr_ = tid & 31;
  int qq = (q8 + 1 + pi) & 7;
  int rm = rr_ >> 1, cc = 16 * (rr_ & 1);

  // x staging: thread covers row sr, 16 cols at c0 of the 16x256 fp32 tile
  int sr = tid >> 4, c0 = (tid & 15) * 16;
  const float* xrow = x + ((size_t)(16 * g + sr) * 512) * 256 + c0;
  {
    int t0 = d ? 511 : 0;
    const float4v* xp = (const float4v*)(xrow + (size_t)t0 * 256);
    float va[16];
    *(float4v*)&va[0] = xp[0]; *(float4v*)&va[4] = xp[1];
    *(float4v*)&va[8] = xp[2]; *(float4v*)&va[12] = xp[3];
    half8 h0, h1, l0, l1;
#pragma unroll
    for (int j = 0; j < 8; ++j) {
      _Float16 hi, lo;
      split2(va[j], hi, lo);     h0[j] = hi; l0[j] = lo;
      split2(va[8 + j], hi, lo); h1[j] = hi; l1[j] = lo;
    }
    *(half8*)(void*)&xhi[0][sr][c0] = h0; *(half8*)(void*)&xhi[0][sr][c0 + 8] = h1;
    *(half8*)(void*)&xlo[0][sr][c0] = l0; *(half8*)(void*)&xlo[0][sr][c0 + 8] = l1;
  }
  __syncthreads();

  for (int ti = 0; ti < 512; ++ti) {
    int t = d ? (511 - ti) : ti;
    int buf = ti & 1;

    // issue next step's x loads + this step's mask loads early
    float4v xa0, xa1, xa2, xa3;
    if (ti < 511) {
      int tn = d ? (510 - ti) : (ti + 1);
      const float4v* xp = (const float4v*)(xrow + (size_t)tn * 256);
      xa0 = xp[0]; xa1 = xp[1]; xa2 = xp[2]; xa3 = xp[3];
    }
    int m0 = 2 * (tid >> 5);
    int mk0 = mask[t * 64 + 16 * g + m0];
    int mk1 = mask[t * 64 + 16 * g + m0 + 1];

    // phase B-issue: speculative first poll round, issued BEFORE phase A so
    // its LLC round trip hides under the x@Wk MFMAs. Validated (and retried
    // if stale) after phase A. Tag rides inside each 8B packet => always safe.
    const u64* hp8 = nullptr;
    u64 v[16];
    if (ti > 0 && tid < 224) {
      int slot2 = (ti - 1) & 1;
      hp8 = hx64 + ((((size_t)(slot2 * 2 + d) * 4 + g) * 8 + qq) * 16 + rm) * 32 + cc;
#pragma unroll
      for (int j = 0; j < 16; ++j)
        v[j] = __hip_atomic_load(hp8 + j, __ATOMIC_RELAXED, __HIP_MEMORY_SCOPE_AGENT);
    }

    // phase A: z = b + x@Wk (split), independent of partner exchange
    float4v zm0 = {bs0, bs0, bs0, bs0}, zm1 = {bs1, bs1, bs1, bs1};
    float4v zc0 = {0.f, 0.f, 0.f, 0.f}, zc1 = {0.f, 0.f, 0.f, 0.f};
#pragma unroll
    for (int kk = 0; kk < 8; ++kk) {
      half8 axh = *(const half8*)(const void*)&xhi[buf][li][32 * kk + 8 * lg];
      half8 axl = *(const half8*)(const void*)&xlo[buf][li][32 * kk + 8 * lg];
      zm0 = __builtin_amdgcn_mfma_f32_16x16x32_f16(axh, wkh[0][kk], zm0, 0, 0, 0);
      zc0 = __builtin_amdgcn_mfma_f32_16x16x32_f16(axh, wkl[0][kk], zc0, 0, 0, 0);
      zc0 = __builtin_amdgcn_mfma_f32_16x16x32_f16(axl, wkh[0][kk], zc0, 0, 0, 0);
      zm1 = __builtin_amdgcn_mfma_f32_16x16x32_f16(axh, wkh[1][kk], zm1, 0, 0, 0);
      zc1 = __builtin_amdgcn_mfma_f32_16x16x32_f16(axh, wkl[1][kk], zc1, 0, 0, 0);
      zc1 = __builtin_amdgcn_mfma_f32_16x16x32_f16(axl, wkh[1][kk], zc1, 0, 0, 0);
    }

    // phase B-validate: accept iff all 16 tags >= ti; else re-load and retry.
    if (ti > 0 && tid < 224) {
      for (;;) {
        u32 mintag = 0xffffffffu;
#pragma unroll
        for (int j = 0; j < 16; ++j) {
          u32 tg = (u32)(v[j] >> 32);
          mintag = tg < mintag ? tg : mintag;
        }
        if (mintag >= (u32)ti) break;
        __builtin_amdgcn_s_sleep(1);
#pragma unroll
        for (int j = 0; j < 16; ++j)
          v[j] = __hip_atomic_load(hp8 + j, __ATOMIC_RELAXED, __HIP_MEMORY_SCOPE_AGENT);
      }
      // unpack: payload is the writer's split pair (no reader-side split2)
      ushort8 h0, h1, l0, l1;
#pragma unroll
      for (int j = 0; j < 8; ++j) {
        u32 d0 = (u32)v[j], d1 = (u32)v[8 + j];
        h0[j] = (u16)(d0 & 0xffffu); l0[j] = (u16)(d0 >> 16);
        h1[j] = (u16)(d1 & 0xffffu); l1[j] = (u16)(d1 >> 16);
      }
      *(ushort8*)(void*)&hhi[rm][32 * qq + cc]     = h0;
      *(ushort8*)(void*)&hhi[rm][32 * qq + cc + 8] = h1;
      *(ushort8*)(void*)&hlo[rm][32 * qq + cc]     = l0;
      *(ushort8*)(void*)&hlo[rm][32 * qq + cc + 8] = l1;
    }
    __syncthreads();  // B2: hhi/hlo complete

    // phase C: z += h @ Wr (split)
#pragma unroll
    for (int kk = 0; kk < 8; ++kk) {
      half8 ahh = *(const half8*)(const void*)&hhi[li][32 * kk + 8 * lg];
      half8 ahl = *(const half8*)(const void*)&hlo[li][32 * kk + 8 * lg];
      zm0 = __builtin_amdgcn_mfma_f32_16x16x32_f16(ahh, wrh[0][kk], zm0, 0, 0, 0);
      zc0 = __builtin_amdgcn_mfma_f32_16x16x32_f16(ahh, wrl[0][kk], zc0, 0, 0, 0);
      zc0 = __builtin_amdgcn_mfma_f32_16x16x32_f16(ahl, wrh[0][kk], zc0, 0, 0, 0);
      zm1 = __builtin_amdgcn_mfma_f32_16x16x32_f16(ahh, wrh[1][kk], zm1, 0, 0, 0);
      zc1 = __builtin_amdgcn_mfma_f32_16x16x32_f16(ahh, wrl[1][kk], zc1, 0, 0, 0);
      zc1 = __builtin_amdgcn_mfma_f32_16x16x32_f16(ahl, wrh[1][kk], zc1, 0, 0, 0);
    }
#pragma unroll
    for (int rr = 0; rr < 4; ++rr) {
      zb[2 * p][4 * lg + rr][16 * sl + li] = clamp30(zm0[rr] + zc0[rr] * LO_ISCALE);
      zb[2 * p + 1][4 * lg + rr][16 * sl + li] = clamp30(zm1[rr] + zc1[rr] * LO_ISCALE);
    }

    // stage x(t+1) into the other buffer (read next iter, after B3)
    if (ti < 511) {
      float va[16];
      *(float4v*)&va[0] = xa0; *(float4v*)&va[4] = xa1;
      *(float4v*)&va[8] = xa2; *(float4v*)&va[12] = xa3;
      half8 h0, h1, l0, l1;
#pragma unroll
      for (int j = 0; j < 8; ++j) {
        _Float16 hi, lo;
        split2(va[j], hi, lo);     h0[j] = hi; l0[j] = lo;
        split2(va[8 + j], hi, lo); h1[j] = hi; l1[j] = lo;
      }
      *(half8*)(void*)&xhi[buf ^ 1][sr][c0] = h0;
      *(half8*)(void*)&xhi[buf ^ 1][sr][c0 + 8] = h1;
      *(half8*)(void*)&xlo[buf ^ 1][sr][c0] = l0;
      *(half8*)(void*)&xlo[buf ^ 1][sr][c0 + 8] = l1;
    }
    __syncthreads();  // B3: zb + x stage ready

    // phase D: state update — thread owns unit-col uo, rows m0,m0+1.
    // Publish = the packet stores themselves; no drain, no flag, no B4.
    int uo = tid & 31;
    int slot = ti & 1;
    u64 tagw = ((u64)(u32)(ti + 1)) << 32;
#pragma unroll
    for (int e2 = 0; e2 < 2; ++e2) {
      int m = m0 + e2;
      float zi = zb[0][m][uo];
      float zf = zb[1][m][uo];
      float zg = zb[2][m][uo];
      float zo = zb[3][m][uo];
      float gi = ftanh(zi), gf = ftanh(zf), gg = ftanh(zg), go = ftanh(zo);
      float cn = gf * cst[e2] + gi * gg;
      float hn = go * ftanh(cn);
      bool mk = (e2 ? mk1 : mk0) != 0;
      cst[e2] = mk ? cn : cst[e2];
      hst[e2] = mk ? hn : hst[e2];
      float hv = hst[e2];
      _Float16 hi, lo; split2(hv, hi, lo);
      u64 pk = (u64)((u32)h2u(hi) | ((u32)h2u(lo) << 16)) | tagw;
      __hip_atomic_store(
          hx64 + ((((size_t)(slot * 2 + d) * 4 + g) * 8 + q8) * 16 + m) * 32 + uo,
          pk, __ATOMIC_RELAXED, __HIP_MEMORY_SCOPE_AGENT);
      hhi[m][32 * q8 + uo] = h2u(hi);
      hlo[m][32 * q8 + uo] = h2u(lo);
    }
    // out stores last: their retire order never gates the packet publication
#pragma unroll
    for (int e2 = 0; e2 < 2; ++e2) {
      int b = 16 * g + m0 + e2;
      out[((size_t)b * 512 + t) * 512 + 256 * d + 32 * q8 + uo] = hst[e2];
    }
  }

  // state_h (fp32)
  {
    int uo = tid & 31;
    int m0 = 2 * (tid >> 5);
#pragma unroll
    for (int e2 = 0; e2 < 2; ++e2) {
      int b = 16 * g + m0 + e2;
      out[(size_t)16777216 + (size_t)b * 512 + 256 * d + 32 * q8 + uo] = hst[e2];
    }
  }
}

extern "C" void kernel_launch(void* const* d_in, const int* in_sizes, int n_in,
                              void* d_out, int out_size, void* d_ws, size_t ws_size,
                              hipStream_t stream) {
  const float* x    = (const float*)d_in[0];
  const float* Wk_f = (const float*)d_in[1];
  const float* Wr_f = (const float*)d_in[2];
  const float* b_f  = (const float*)d_in[3];
  const float* Wk_b = (const float*)d_in[4];
  const float* Wr_b = (const float*)d_in[5];
  const float* b_b  = (const float*)d_in[6];
  char* ws = (char*)d_ws;
  u64* hx64  = (u64*)(ws + OFF_HX);
  unsigned char* maskp = (unsigned char*)(ws + OFF_MASK);
  float* out = (float*)d_out;

  k_mask<<<8192, 256, 0, stream>>>(x, maskp, hx64);
  k_scan<<<64, 256, 0, stream>>>(Wk_f, Wr_f, b_f, Wk_b, Wr_b, b_b, x, maskp, hx64, out);
}